// Round 6
// baseline (364.755 us; speedup 1.0000x reference)
//
#include <hip/hip_runtime.h>
#include <hip/hip_fp16.h>
#include <math.h>

// Problem constants (fixed by reference setup_inputs)
#define N_NODES 100000
#define N_INCID 2000000
#define HIDDEN  128
#define N_HE    100000

#define EPB 1024                                   // edges per fill block
#define FILL_BLOCKS ((N_INCID + EPB - 1) / EPB)    // 1954
#define PREP_BLOCKS ((N_NODES + 3) / 4)            // 25000

__device__ inline float4 h4_to_f4(uint2 p) {
    __half2 a = *(__half2*)&p.x;
    __half2 b = *(__half2*)&p.y;
    float2 fa = __half22float2(a);
    float2 fb = __half22float2(b);
    return make_float4(fa.x, fa.y, fb.x, fb.y);
}

// K1 (fused): fill blocks do CSR slot-assign with ILP-4 (4 independent
// atomic->store chains per lane = 256 outstanding atomics/wave); prep blocks
// build en[] + fp16 feats copy (BW-bound). Independent work -> co-resident
// waves overlap atomic latency with streaming BW.
__global__ void prep_fill_kernel(const float* __restrict__ nf,
                                 const float* __restrict__ W,
                                 const int* __restrict__ idx,
                                 float* __restrict__ en,
                                 __half2* __restrict__ nfh2,
                                 int* __restrict__ counts,
                                 int* __restrict__ csr) {
    int b = blockIdx.x;
    if (b < FILL_BLOCKS) {
        int base = b * EPB;
        int e = base + threadIdx.x;
        if (base + EPB <= N_INCID) {
            int he[4], nd[4], slot[4];
            #pragma unroll
            for (int k = 0; k < 4; ++k) {
                he[k] = idx[N_INCID + e + 256 * k];
                nd[k] = idx[e + 256 * k];
            }
            #pragma unroll
            for (int k = 0; k < 4; ++k) slot[k] = atomicAdd(&counts[he[k]], 1);
            #pragma unroll
            for (int k = 0; k < 4; ++k)
                if (slot[k] < 64) csr[(size_t)he[k] * 64 + slot[k]] = nd[k];
        } else {
            #pragma unroll
            for (int k = 0; k < 4; ++k) {
                int ek = e + 256 * k;
                if (ek < N_INCID) {
                    int he = idx[N_INCID + ek];
                    int nd = idx[ek];
                    int slot = atomicAdd(&counts[he], 1);
                    if (slot < 64) csr[(size_t)he * 64 + slot] = nd;
                }
            }
        }
    } else {
        int wave = threadIdx.x >> 6, lane = threadIdx.x & 63;
        int n = (b - FILL_BLOCKS) * 4 + wave;
        if (n >= N_NODES) return;
        const float2* nf2 = (const float2*)nf;
        const float2* w2  = (const float2*)W;
        float2 v = nf2[(size_t)n * 64 + lane];
        float2 w = w2[lane];
        float p = v.x * w.x + v.y * w.y;
        #pragma unroll
        for (int o = 32; o > 0; o >>= 1) p += __shfl_xor(p, o, 64);
        if (lane == 0) en[n] = __expf(p);
        nfh2[(size_t)n * 64 + lane] = __floats2half2_rn(v.x, v.y);
    }
}

// K2: wave per hyperedge. Softmax denom = shfl-reduction of lanes' en values
// (no atomics). Gather: 16 rows/iter, 8 outstanding 256B row-loads per
// half-wave (32 lanes x 8B fp16 = one full row per instruction).
__global__ void compute_kernel_h(const int* __restrict__ counts,
                                 const int* __restrict__ csr,
                                 const float* __restrict__ en,
                                 const uint2* __restrict__ nfh4,
                                 const int* __restrict__ idx,
                                 float* __restrict__ out) {
    int wave = threadIdx.x >> 6, lane = threadIdx.x & 63;
    int he = blockIdx.x * 4 + wave;
    if (he >= N_HE) return;
    int l32 = lane & 31, half = lane >> 5;
    int deg = counts[he];
    float4 acc = make_float4(0.f, 0.f, 0.f, 0.f);

    if (deg <= 64) {
        int nd_l = 0; float e_l = 0.f;
        if (lane < deg) { nd_l = csr[(size_t)he * 64 + lane]; e_l = en[nd_l]; }
        float dsum = e_l;
        #pragma unroll
        for (int o = 32; o > 0; o >>= 1) dsum += __shfl_xor(dsum, o, 64);
        float w_l = e_l * (1.0f / fmaxf(dsum, 1e-20f));   // deg==0: loop empty

        int degR = (deg + 15) & ~15;    // padded slots: nd=0, w=0 (row 0 L1-hot)
        for (int j = 0; j < degR; j += 16) {
            int   n[8]; float wgt[8]; uint2 p[8];
            #pragma unroll
            for (int k = 0; k < 8; ++k) {
                int r = j + 2 * k + half;           // < 64 always (degR<=64)
                n[k]   = __shfl(nd_l, r, 64);
                wgt[k] = __shfl(w_l,  r, 64);
            }
            #pragma unroll
            for (int k = 0; k < 8; ++k) p[k] = nfh4[(size_t)n[k] * 32 + l32];
            #pragma unroll
            for (int k = 0; k < 8; ++k) {
                float4 v = h4_to_f4(p[k]);
                acc.x += wgt[k] * v.x; acc.y += wgt[k] * v.y;
                acc.z += wgt[k] * v.z; acc.w += wgt[k] * v.w;
            }
        }
    } else {
        // exact fallback (P ~ 1e-10 for Poisson(20) degrees): scan all edges
        float dsum = 0.f;
        for (int e = lane; e < N_INCID; e += 64)
            if (idx[N_INCID + e] == he) dsum += en[idx[e]];
        #pragma unroll
        for (int o = 32; o > 0; o >>= 1) dsum += __shfl_xor(dsum, o, 64);
        float inv = 1.0f / fmaxf(dsum, 1e-20f);
        for (int e = half; e < N_INCID; e += 2) {
            if (idx[N_INCID + e] == he) {
                int nd = idx[e];
                float w = en[nd] * inv;
                float4 v = h4_to_f4(nfh4[(size_t)nd * 32 + l32]);
                acc.x += w * v.x; acc.y += w * v.y;
                acc.z += w * v.z; acc.w += w * v.w;
            }
        }
    }
    acc.x += __shfl_xor(acc.x, 32, 64);
    acc.y += __shfl_xor(acc.y, 32, 64);
    acc.z += __shfl_xor(acc.z, 32, 64);
    acc.w += __shfl_xor(acc.w, 32, 64);
    if (half == 0) ((float4*)out)[(size_t)he * 32 + l32] = acc;
}

extern "C" void kernel_launch(void* const* d_in, const int* in_sizes, int n_in,
                              void* d_out, int out_size, void* d_ws, size_t ws_size,
                              hipStream_t stream) {
    const float* nf  = (const float*)d_in[0];
    const int*   idx = (const int*)d_in[1];   // int32: harness downcasts int64
    const float* W   = (const float*)d_in[3];
    float* out = (float*)d_out;
    char* ws = (char*)d_ws;

    int*     counts = (int*)(ws + 0);           // 400 KB
    float*   en     = (float*)(ws + 400000);    // 400 KB
    __half2* nfh2   = (__half2*)(ws + 800000);  // 25.6 MB
    int*     csr    = (int*)(ws + 26400000);    // 25.6 MB  (total ~52 MB, proven R4)

    hipMemsetAsync(counts, 0, N_HE * sizeof(int), stream);
    prep_fill_kernel<<<FILL_BLOCKS + PREP_BLOCKS, 256, 0, stream>>>(
        nf, W, idx, en, nfh2, counts, csr);
    compute_kernel_h<<<(N_HE + 3) / 4, 256, 0, stream>>>(
        counts, csr, en, (const uint2*)nfh2, idx, out);
}

// Round 7
// 330.941 us; speedup vs baseline: 1.1022x; 1.1022x over previous
//
#include <hip/hip_runtime.h>
#include <hip/hip_fp16.h>
#include <math.h>

// Problem constants (fixed by reference setup_inputs)
#define N_NODES 100000
#define N_INCID 2000000
#define HIDDEN  128
#define N_HE    100000

#define EPB 1024                                   // edges per fill block (ILP-4)
#define FILL_BLOCKS ((N_INCID + EPB - 1) / EPB)    // 1954
#define PREP_BLOCKS ((N_NODES + 3) / 4)            // 25000

__device__ inline float4 h4_to_f4(uint2 p) {
    __half2 a = *(__half2*)&p.x;
    __half2 b = *(__half2*)&p.y;
    float2 fa = __half22float2(a);
    float2 fb = __half22float2(b);
    return make_float4(fa.x, fa.y, fb.x, fb.y);
}

// K1 (fused):
//  - fill blocks: linked-list CSR build. prev = atomicExch(head[he], e) on a
//    400 KB L2-resident array; next8[e] = {nd, prev} is a COALESCED 8 B store
//    (this replaces R6's scattered 4 B stores into 25.6 MB — the measured
//    146 MB write-amplification wall).
//  - prep blocks: en[n] = exp(dot(f[n],W)) + fp16 copy of feats (BW-bound).
__global__ void prep_fill_kernel(const float* __restrict__ nf,
                                 const float* __restrict__ W,
                                 const int* __restrict__ idx,
                                 float* __restrict__ en,
                                 __half2* __restrict__ nfh2,
                                 int* __restrict__ head,
                                 int2* __restrict__ next8) {
    int b = blockIdx.x;
    if (b < FILL_BLOCKS) {
        int base = b * EPB;
        int e = base + threadIdx.x;
        if (base + EPB <= N_INCID) {
            int he[4], nd[4], prev[4];
            #pragma unroll
            for (int k = 0; k < 4; ++k) {
                he[k] = idx[N_INCID + e + 256 * k];
                nd[k] = idx[e + 256 * k];
            }
            #pragma unroll
            for (int k = 0; k < 4; ++k)
                prev[k] = atomicExch(&head[he[k]], e + 256 * k);
            #pragma unroll
            for (int k = 0; k < 4; ++k)
                next8[e + 256 * k] = make_int2(nd[k], prev[k]);
        } else {
            #pragma unroll
            for (int k = 0; k < 4; ++k) {
                int ek = e + 256 * k;
                if (ek < N_INCID) {
                    int he = idx[N_INCID + ek];
                    int nd = idx[ek];
                    int prev = atomicExch(&head[he], ek);
                    next8[ek] = make_int2(nd, prev);
                }
            }
        }
    } else {
        int wave = threadIdx.x >> 6, lane = threadIdx.x & 63;
        int n = (b - FILL_BLOCKS) * 4 + wave;
        if (n >= N_NODES) return;
        const float2* nf2 = (const float2*)nf;
        const float2* w2  = (const float2*)W;
        float2 v = nf2[(size_t)n * 64 + lane];
        float2 w = w2[lane];
        float p = v.x * w.x + v.y * w.y;
        #pragma unroll
        for (int o = 32; o > 0; o >>= 1) p += __shfl_xor(p, o, 64);
        if (lane == 0) en[n] = __expf(p);
        nfh2[(size_t)n * 64 + lane] = __floats2half2_rn(v.x, v.y);
    }
}

// K2: one hyperedge per HALF-WAVE (two independent chains per wave for MLP).
// Walk the linked list: each hop is one broadcast 8 B load {nd, next}; all 32
// lanes gather the fp16 row (32 x 8 B = 256 B = full row) and accumulate
// acc += en[nd]*row, denom += en[nd] (denom identical in every lane — no
// reduction). Normalize by 1/denom at the end (softmax w/o max-subtraction,
// validated R4-R6). Any degree handled uniformly; empty he -> acc=0.
__global__ void compute_kernel_h(const int* __restrict__ head,
                                 const int2* __restrict__ next8,
                                 const float* __restrict__ en,
                                 const uint2* __restrict__ nfh4,
                                 float* __restrict__ out) {
    int wave = threadIdx.x >> 6, lane = threadIdx.x & 63;
    int half = lane >> 5, l32 = lane & 31;
    int he = blockIdx.x * 8 + wave * 2 + half;
    if (he >= N_HE) return;

    float4 acc = make_float4(0.f, 0.f, 0.f, 0.f);
    float denom = 0.f;
    int e = head[he];
    while (e >= 0) {
        int2 p = next8[e];                       // broadcast (same addr in half)
        float w = en[p.x];                       // broadcast
        float4 v = h4_to_f4(nfh4[(size_t)p.x * 32 + l32]);
        acc.x += w * v.x; acc.y += w * v.y;
        acc.z += w * v.z; acc.w += w * v.w;
        denom += w;
        e = p.y;
    }
    float inv = 1.0f / fmaxf(denom, 1e-20f);
    acc.x *= inv; acc.y *= inv; acc.z *= inv; acc.w *= inv;
    ((float4*)out)[(size_t)he * 32 + l32] = acc;
}

extern "C" void kernel_launch(void* const* d_in, const int* in_sizes, int n_in,
                              void* d_out, int out_size, void* d_ws, size_t ws_size,
                              hipStream_t stream) {
    const float* nf  = (const float*)d_in[0];
    const int*   idx = (const int*)d_in[1];   // int32: harness downcasts int64
    const float* W   = (const float*)d_in[3];
    float* out = (float*)d_out;
    char* ws = (char*)d_ws;

    int*     head  = (int*)(ws + 0);            // 400 KB
    float*   en    = (float*)(ws + 400000);     // 400 KB
    __half2* nfh2  = (__half2*)(ws + 800000);   // 25.6 MB
    int2*    next8 = (int2*)(ws + 26400000);    // 16 MB   (total 42.4 MB < proven 52 MB)

    hipMemsetAsync(head, 0xFF, N_HE * sizeof(int), stream);   // head[he] = -1
    prep_fill_kernel<<<FILL_BLOCKS + PREP_BLOCKS, 256, 0, stream>>>(
        nf, W, idx, en, nfh2, head, next8);
    compute_kernel_h<<<(N_HE + 7) / 8, 256, 0, stream>>>(
        head, next8, en, (const uint2*)nfh2, out);
}